// Round 7
// baseline (1928.931 us; speedup 1.0000x reference)
//
#include <hip/hip_runtime.h>
#include <math.h>

#define N_NODE 100000
#define DEPTH  10
#define N_EDGE 1600000
#define D_FEAT 32
#define D_OUT  ((DEPTH + 1) * D_FEAT)   // 352 floats per node in output
#define NB_SCAN ((N_NODE + 255) / 256)  // 391 scan blocks
#define SPMM_BLOCKS 768                 // 3 blocks/CU needed; 4/CU available -> safe co-residency

// clang-native vector types (accepted by __builtin_nontemporal_*)
typedef float        f32x4 __attribute__((ext_vector_type(4)));
typedef unsigned int u32x4 __attribute__((ext_vector_type(4)));
typedef int          i32x2 __attribute__((ext_vector_type(2)));

// ---------------------------------------------------------------------------
// bf16 helpers (bit-level, RTN-even)
// ---------------------------------------------------------------------------
__device__ inline unsigned short f32_to_bf16(float f) {
    unsigned int b = __float_as_uint(f);
    unsigned int r = (b + 0x7FFFu + ((b >> 16) & 1u)) >> 16;
    return (unsigned short)r;
}
__device__ inline unsigned int pack_bf16x2(float lo, float hi) {
    return (unsigned int)f32_to_bf16(lo) | ((unsigned int)f32_to_bf16(hi) << 16);
}

// ---------------------------------------------------------------------------
// Phase 1: degree count (in-degree over `row`)
// ---------------------------------------------------------------------------
__global__ void count_kernel(const int* __restrict__ row, int* __restrict__ cnt, int E) {
    int e = blockIdx.x * blockDim.x + threadIdx.x;
    if (e < E) atomicAdd(&cnt[row[e]], 1);
}

// ---------------------------------------------------------------------------
// Phase 2: hierarchical exclusive scan (3 kernels)
// ---------------------------------------------------------------------------
__device__ inline int wave_incl_scan(int v) {
    int lane = threadIdx.x & 63;
    #pragma unroll
    for (int off = 1; off < 64; off <<= 1) {
        int t = __shfl_up(v, off, 64);
        if (lane >= off) v += t;
    }
    return v;
}

__global__ void blockscan_kernel(const int* __restrict__ cnt, int* __restrict__ rowStart,
                                 int* __restrict__ blockSums, int n) {
    __shared__ int partials[4];
    int i = blockIdx.x * 256 + threadIdx.x;
    int v = (i < n) ? cnt[i] : 0;
    int incl = wave_incl_scan(v);
    int wid = threadIdx.x >> 6, lane = threadIdx.x & 63;
    if (lane == 63) partials[wid] = incl;
    __syncthreads();
    int woff = 0;
    #pragma unroll
    for (int w = 0; w < 4; ++w) woff += (w < wid) ? partials[w] : 0;
    if (i < n) rowStart[i] = woff + incl - v;               // block-local exclusive
    if (threadIdx.x == 255) blockSums[blockIdx.x] = woff + incl;
}

__global__ void scansums_kernel(int* __restrict__ blockSums, int nb) {
    __shared__ int partials[8];
    int i = threadIdx.x;                                    // 512 threads
    int v = (i < nb) ? blockSums[i] : 0;
    int incl = wave_incl_scan(v);
    int wid = i >> 6, lane = i & 63;
    if (lane == 63) partials[wid] = incl;
    __syncthreads();
    int woff = 0;
    #pragma unroll
    for (int w = 0; w < 8; ++w) woff += (w < wid) ? partials[w] : 0;
    if (i < nb) blockSums[i] = woff + incl - v;             // exclusive
    if (i == 511) blockSums[nb] = woff + incl;              // grand total
}

__global__ void addoffs_kernel(int* __restrict__ rowStart, const int* __restrict__ blockSums,
                               int n, int nb) {
    int i = blockIdx.x * 256 + threadIdx.x;
    if (i < n)  rowStart[i] += blockSums[i >> 8];
    if (i == n) rowStart[n] = blockSums[nb];
}

// ---------------------------------------------------------------------------
// Phase 3: dinv = (deg<0.5 ? deg+1 : deg)^-0.5
// ---------------------------------------------------------------------------
__global__ void dinv_kernel(const int* __restrict__ cnt, float* __restrict__ dinv, int n) {
    int i = blockIdx.x * blockDim.x + threadIdx.x;
    if (i < n) {
        float d = (float)cnt[i];
        if (d < 0.5f) d += 1.0f;
        dinv[i] = 1.0f / sqrtf(d);
    }
}

// ---------------------------------------------------------------------------
// Phase 4: scatter edges to CSR as combined 8B {col, val} entries (NT store).
// ---------------------------------------------------------------------------
__global__ void scatter_kernel(const int* __restrict__ row, const int* __restrict__ col,
                               const float* __restrict__ eattr,
                               const int* __restrict__ rowStart, int* __restrict__ cnt,
                               const float* __restrict__ dinv,
                               i32x2* __restrict__ csr, int E) {
    int e = blockIdx.x * blockDim.x + threadIdx.x;
    if (e < E) {
        int r = row[e], c = col[e];
        int p = rowStart[r] + atomicSub(&cnt[r], 1) - 1;
        float val = dinv[r] * eattr[e] * dinv[c];
        i32x2 ent; ent.x = c; ent.y = __float_as_int(val);
        __builtin_nontemporal_store(ent, &csr[p]);
    }
}

// ---------------------------------------------------------------------------
// alphas_t[L] = tanh(alphas[L]) (BASE_ALPHA = 1)
// ---------------------------------------------------------------------------
__global__ void alpha_kernel(const float* __restrict__ alphas, float* __restrict__ alphaT) {
    int i = threadIdx.x;
    if (i <= DEPTH) alphaT[i] = tanhf(alphas[i]);
}

// ---------------------------------------------------------------------------
// x_0: out[node,0,:] = x (fp32, nt) and h0[node,:] = bf16(x) (plain store)
// ---------------------------------------------------------------------------
__global__ void copyx_kernel(const f32x4* __restrict__ x4, f32x4* __restrict__ out4,
                             unsigned int* __restrict__ h0) {
    int i = blockIdx.x * blockDim.x + threadIdx.x;
    if (i < N_NODE * 8) {
        int node = i >> 3, q = i & 7;
        f32x4 v = x4[i];
        __builtin_nontemporal_store(v, &out4[(size_t)node * 88 + q]);
        h0[i * 2]     = pack_bf16x2(v.x, v.y);
        h0[i * 2 + 1] = pack_bf16x2(v.z, v.w);
    }
}

// ---------------------------------------------------------------------------
// Phase 5: ALL 10 SpMM levels in ONE persistent kernel, software grid barrier
// between levels. 768 blocks x 256 thr, __launch_bounds__(256,4) caps VGPR at
// 128 -> >=4 blocks/CU capacity, 3/CU needed: co-residency guaranteed.
// Barrier: monotonic device-scope counter, target = SPMM_BLOCKS * L.
// lane = (s,q): s = edge slot (0..15), q = feat oct (16B of bf16 h row).
// ---------------------------------------------------------------------------
__global__ __launch_bounds__(256, 4) void spmm_fused(const int* __restrict__ rowStart,
                                                     const i32x2* __restrict__ csr,
                                                     const float* __restrict__ alphaT,
                                                     u32x4* __restrict__ h0,
                                                     u32x4* __restrict__ h1,
                                                     f32x4* __restrict__ out4,
                                                     int* __restrict__ bar) {
    int lane = threadIdx.x & 63;
    int s = lane >> 2;                 // edge slot (16)
    int q = lane & 3;                  // feat oct (4 x 8 feats)
    int wave   = (int)((blockIdx.x * 256 + threadIdx.x) >> 6);
    const int nwaves = SPMM_BLOCKS * 4;

    for (int L = 1; L <= DEPTH; ++L) {
        const u32x4* __restrict__ hp = (L & 1) ? h0 : h1;
        u32x4*       __restrict__ hc = (L & 1) ? h1 : h0;
        float a = alphaT[L];

        for (int rowid = wave; rowid < N_NODE; rowid += nwaves) {
            int start = rowStart[rowid];
            int end   = rowStart[rowid + 1];

            float acc[8] = {0.f, 0.f, 0.f, 0.f, 0.f, 0.f, 0.f, 0.f};
            for (int e = start + s; e < end; e += 16) {
                i32x2 cv = __builtin_nontemporal_load(&csr[e]);
                float v  = __int_as_float(cv.y);
                u32x4 h  = hp[(size_t)cv.x * 4 + q];
                acc[0] += v * __uint_as_float(h.x << 16);
                acc[1] += v * __uint_as_float(h.x & 0xFFFF0000u);
                acc[2] += v * __uint_as_float(h.y << 16);
                acc[3] += v * __uint_as_float(h.y & 0xFFFF0000u);
                acc[4] += v * __uint_as_float(h.z << 16);
                acc[5] += v * __uint_as_float(h.z & 0xFFFF0000u);
                acc[6] += v * __uint_as_float(h.w << 16);
                acc[7] += v * __uint_as_float(h.w & 0xFFFF0000u);
            }

            #pragma unroll
            for (int m = 4; m < 64; m <<= 1) {
                #pragma unroll
                for (int k = 0; k < 8; ++k) acc[k] += __shfl_xor(acc[k], m, 64);
            }

            if (s == 0) {   // lanes 0..3 hold feats q*8..q*8+7
                #pragma unroll
                for (int k = 0; k < 8; ++k) acc[k] *= a;
                size_t ob = (size_t)rowid * 88 + L * 8 + q * 2;
                f32x4 o0; o0.x = acc[0]; o0.y = acc[1]; o0.z = acc[2]; o0.w = acc[3];
                f32x4 o1; o1.x = acc[4]; o1.y = acc[5]; o1.z = acc[6]; o1.w = acc[7];
                __builtin_nontemporal_store(o0, &out4[ob]);
                __builtin_nontemporal_store(o1, &out4[ob + 1]);
                if (L < DEPTH) {
                    u32x4 hh;
                    hh.x = pack_bf16x2(acc[0], acc[1]);
                    hh.y = pack_bf16x2(acc[2], acc[3]);
                    hh.z = pack_bf16x2(acc[4], acc[5]);
                    hh.w = pack_bf16x2(acc[6], acc[7]);
                    hc[(size_t)rowid * 4 + q] = hh;   // plain: keep in L2
                }
            }
        }

        if (L < DEPTH) {   // grid barrier: all blocks finish level L
            __syncthreads();
            if (threadIdx.x == 0) {
                __threadfence();   // device-scope release of h_cur writes
                __hip_atomic_fetch_add(bar, 1, __ATOMIC_RELEASE, __HIP_MEMORY_SCOPE_AGENT);
                int target = SPMM_BLOCKS * L;
                while (__hip_atomic_load(bar, __ATOMIC_ACQUIRE, __HIP_MEMORY_SCOPE_AGENT) < target) {
                    __builtin_amdgcn_s_sleep(8);
                }
            }
            __syncthreads();
        }
    }
}

// ---------------------------------------------------------------------------
extern "C" void kernel_launch(void* const* d_in, const int* in_sizes, int n_in,
                              void* d_out, int out_size, void* d_ws, size_t ws_size,
                              hipStream_t stream) {
    const float* x      = (const float*)d_in[0];
    const int*   eidx   = (const int*)d_in[1];     // (2, E): row = [0,E), col = [E,2E)
    const float* eattr  = (const float*)d_in[2];
    const float* alphas = (const float*)d_in[3];
    float* out = (float*)d_out;

    const int* row = eidx;
    const int* col = eidx + N_EDGE;

    // ---- workspace partition (256B aligned) ----
    char* p = (char*)d_ws;
    auto alloc = [&](size_t bytes) { char* r = p; p += (bytes + 255) & ~(size_t)255; return (void*)r; };
    int*   cnt       = (int*)  alloc((size_t)N_NODE * 4);
    int*   rowStart  = (int*)  alloc((size_t)(N_NODE + 1) * 4);
    int*   blockSums = (int*)  alloc((size_t)(NB_SCAN + 1) * 4);
    float* dinv      = (float*)alloc((size_t)N_NODE * 4);
    float* alphaT    = (float*)alloc(64);
    int*   bar       = (int*)  alloc(256);
    u32x4* h0        = (u32x4*)alloc((size_t)N_NODE * 64);  // bf16 [N][32]
    u32x4* h1        = (u32x4*)alloc((size_t)N_NODE * 64);
    i32x2* csr       = (i32x2*)alloc((size_t)N_EDGE * 8);
    (void)ws_size; (void)in_sizes; (void)n_in; (void)out_size;

    (void)hipMemsetAsync(cnt, 0, (size_t)N_NODE * 4, stream);
    (void)hipMemsetAsync(bar, 0, 4, stream);

    const int TB = 256;
    int eBlocks = (N_EDGE + TB - 1) / TB;
    int nBlocks = (N_NODE + TB - 1) / TB;

    count_kernel<<<eBlocks, TB, 0, stream>>>(row, cnt, N_EDGE);
    blockscan_kernel<<<NB_SCAN, TB, 0, stream>>>(cnt, rowStart, blockSums, N_NODE);
    scansums_kernel<<<1, 512, 0, stream>>>(blockSums, NB_SCAN);
    addoffs_kernel<<<(N_NODE + 1 + TB - 1) / TB, TB, 0, stream>>>(rowStart, blockSums, N_NODE, NB_SCAN);
    dinv_kernel<<<nBlocks, TB, 0, stream>>>(cnt, dinv, N_NODE);
    scatter_kernel<<<eBlocks, TB, 0, stream>>>(row, col, eattr, rowStart, cnt, dinv, csr, N_EDGE);
    alpha_kernel<<<1, 64, 0, stream>>>(alphas, alphaT);
    copyx_kernel<<<(N_NODE * 8 + TB - 1) / TB, TB, 0, stream>>>((const f32x4*)x, (f32x4*)out,
                                                                (unsigned int*)h0);

    spmm_fused<<<SPMM_BLOCKS, TB, 0, stream>>>(rowStart, csr, alphaT, h0, h1,
                                               (f32x4*)out, bar);
}

// Round 8
// 1039.428 us; speedup vs baseline: 1.8558x; 1.8558x over previous
//
#include <hip/hip_runtime.h>
#include <math.h>

#define N_NODE 100000
#define DEPTH  10
#define N_EDGE 1600000
#define D_FEAT 32
#define D_OUT  ((DEPTH + 1) * D_FEAT)   // 352 floats per node in output
#define NB_SCAN ((N_NODE + 255) / 256)  // 391 scan blocks

// clang-native vector types (accepted by __builtin_nontemporal_*)
typedef float        f32x4 __attribute__((ext_vector_type(4)));
typedef unsigned int u32x4 __attribute__((ext_vector_type(4)));
typedef int          i32x2 __attribute__((ext_vector_type(2)));

// ---------------------------------------------------------------------------
// bf16 helpers (bit-level, RTN-even)
// ---------------------------------------------------------------------------
__device__ inline unsigned short f32_to_bf16(float f) {
    unsigned int b = __float_as_uint(f);
    unsigned int r = (b + 0x7FFFu + ((b >> 16) & 1u)) >> 16;
    return (unsigned short)r;
}
__device__ inline unsigned int pack_bf16x2(float lo, float hi) {
    return (unsigned int)f32_to_bf16(lo) | ((unsigned int)f32_to_bf16(hi) << 16);
}

// ---------------------------------------------------------------------------
// Phase 1: degree count (in-degree over `row`)
// ---------------------------------------------------------------------------
__global__ void count_kernel(const int* __restrict__ row, int* __restrict__ cnt, int E) {
    int e = blockIdx.x * blockDim.x + threadIdx.x;
    if (e < E) atomicAdd(&cnt[row[e]], 1);
}

// ---------------------------------------------------------------------------
// Phase 2: hierarchical exclusive scan (3 kernels)
// ---------------------------------------------------------------------------
__device__ inline int wave_incl_scan(int v) {
    int lane = threadIdx.x & 63;
    #pragma unroll
    for (int off = 1; off < 64; off <<= 1) {
        int t = __shfl_up(v, off, 64);
        if (lane >= off) v += t;
    }
    return v;
}

__global__ void blockscan_kernel(const int* __restrict__ cnt, int* __restrict__ rowStart,
                                 int* __restrict__ blockSums, int n) {
    __shared__ int partials[4];
    int i = blockIdx.x * 256 + threadIdx.x;
    int v = (i < n) ? cnt[i] : 0;
    int incl = wave_incl_scan(v);
    int wid = threadIdx.x >> 6, lane = threadIdx.x & 63;
    if (lane == 63) partials[wid] = incl;
    __syncthreads();
    int woff = 0;
    #pragma unroll
    for (int w = 0; w < 4; ++w) woff += (w < wid) ? partials[w] : 0;
    if (i < n) rowStart[i] = woff + incl - v;               // block-local exclusive
    if (threadIdx.x == 255) blockSums[blockIdx.x] = woff + incl;
}

__global__ void scansums_kernel(int* __restrict__ blockSums, int nb) {
    __shared__ int partials[8];
    int i = threadIdx.x;                                    // 512 threads
    int v = (i < nb) ? blockSums[i] : 0;
    int incl = wave_incl_scan(v);
    int wid = i >> 6, lane = i & 63;
    if (lane == 63) partials[wid] = incl;
    __syncthreads();
    int woff = 0;
    #pragma unroll
    for (int w = 0; w < 8; ++w) woff += (w < wid) ? partials[w] : 0;
    if (i < nb) blockSums[i] = woff + incl - v;             // exclusive
    if (i == 511) blockSums[nb] = woff + incl;              // grand total
}

__global__ void addoffs_kernel(int* __restrict__ rowStart, const int* __restrict__ blockSums,
                               int n, int nb) {
    int i = blockIdx.x * 256 + threadIdx.x;
    if (i < n)  rowStart[i] += blockSums[i >> 8];
    if (i == n) rowStart[n] = blockSums[nb];
}

// ---------------------------------------------------------------------------
// Phase 3: dinv = (deg<0.5 ? deg+1 : deg)^-0.5
// ---------------------------------------------------------------------------
__global__ void dinv_kernel(const int* __restrict__ cnt, float* __restrict__ dinv, int n) {
    int i = blockIdx.x * blockDim.x + threadIdx.x;
    if (i < n) {
        float d = (float)cnt[i];
        if (d < 0.5f) d += 1.0f;
        dinv[i] = 1.0f / sqrtf(d);
    }
}

// ---------------------------------------------------------------------------
// Phase 4: scatter edges to CSR as combined 8B {col, val} entries (NT store).
// ---------------------------------------------------------------------------
__global__ void scatter_kernel(const int* __restrict__ row, const int* __restrict__ col,
                               const float* __restrict__ eattr,
                               const int* __restrict__ rowStart, int* __restrict__ cnt,
                               const float* __restrict__ dinv,
                               i32x2* __restrict__ csr, int E) {
    int e = blockIdx.x * blockDim.x + threadIdx.x;
    if (e < E) {
        int r = row[e], c = col[e];
        int p = rowStart[r] + atomicSub(&cnt[r], 1) - 1;
        float val = dinv[r] * eattr[e] * dinv[c];
        i32x2 ent; ent.x = c; ent.y = __float_as_int(val);
        __builtin_nontemporal_store(ent, &csr[p]);
    }
}

// ---------------------------------------------------------------------------
// alphas_t[L] = tanh(alphas[L]) (BASE_ALPHA = 1)
// ---------------------------------------------------------------------------
__global__ void alpha_kernel(const float* __restrict__ alphas, float* __restrict__ alphaT) {
    int i = threadIdx.x;
    if (i <= DEPTH) alphaT[i] = tanhf(alphas[i]);
}

// ---------------------------------------------------------------------------
// x_0: out[node,0,:] = x (fp32, nt); h0A = bf16(x[:, 0:16]); h0B = bf16(x[:,16:32])
// thread i: node = i>>3, q = i&7 -> feats 4q..4q+3; half = q>>2.
// h-half layout (u32 words): word w of node = feats {2w, 2w+1} of that half.
// ---------------------------------------------------------------------------
__global__ void copyx_kernel(const f32x4* __restrict__ x4, f32x4* __restrict__ out4,
                             unsigned int* __restrict__ h0A, unsigned int* __restrict__ h0B) {
    int i = blockIdx.x * blockDim.x + threadIdx.x;
    if (i < N_NODE * 8) {
        int node = i >> 3, q = i & 7;
        f32x4 v = x4[i];
        __builtin_nontemporal_store(v, &out4[(size_t)node * 88 + q]);
        unsigned int* hh = (q < 4) ? h0A : h0B;
        int w = (q & 3) * 2;                    // words 2(q&3), 2(q&3)+1
        hh[(size_t)node * 8 + w]     = pack_bf16x2(v.x, v.y);
        hh[(size_t)node * 8 + w + 1] = pack_bf16x2(v.z, v.w);
    }
}

// ---------------------------------------------------------------------------
// Phase 5 (x20): SpMM level L over ONE FEATURE HALF (16 feats).
// Gather window = N_NODE*16*2B = 3.2 MB -> fits every XCD's 4 MB L2.
// One wave per row. lane = (s,q): s = lane>>1 (32 edge slots), q = lane&1
// (16B = 8 feats of the 32B half-row). One iteration covers deg<=32.
// csr NT (streamed, keep L2 for h); out NT (never re-read); h_cur plain.
// ---------------------------------------------------------------------------
__global__ __launch_bounds__(256) void spmm_half(const int* __restrict__ rowStart,
                                                 const i32x2* __restrict__ csr,
                                                 const float* __restrict__ alphaT,
                                                 int L, int half,
                                                 const u32x4* __restrict__ h_prev,
                                                 u32x4* __restrict__ h_cur,
                                                 f32x4* __restrict__ out4) {
    int rowid = (int)((blockIdx.x * 256 + threadIdx.x) >> 6);
    if (rowid >= N_NODE) return;
    int lane = threadIdx.x & 63;
    int s = lane >> 1;                 // edge slot (32)
    int q = lane & 1;                  // 8-feat group within the half

    int start = rowStart[rowid];
    int end   = rowStart[rowid + 1];

    float acc[8] = {0.f, 0.f, 0.f, 0.f, 0.f, 0.f, 0.f, 0.f};
    for (int e = start + s; e < end; e += 32) {
        i32x2 cv = __builtin_nontemporal_load(&csr[e]);
        float v  = __int_as_float(cv.y);
        u32x4 h  = h_prev[(size_t)cv.x * 2 + q];   // 16B of the 32B row (pair-coalesced)
        acc[0] += v * __uint_as_float(h.x << 16);
        acc[1] += v * __uint_as_float(h.x & 0xFFFF0000u);
        acc[2] += v * __uint_as_float(h.y << 16);
        acc[3] += v * __uint_as_float(h.y & 0xFFFF0000u);
        acc[4] += v * __uint_as_float(h.z << 16);
        acc[5] += v * __uint_as_float(h.z & 0xFFFF0000u);
        acc[6] += v * __uint_as_float(h.w << 16);
        acc[7] += v * __uint_as_float(h.w & 0xFFFF0000u);
    }

    // reduce across the 32 edge slots (xor 2,4,8,16,32 preserves q = bit0)
    #pragma unroll
    for (int m = 2; m < 64; m <<= 1) {
        #pragma unroll
        for (int k = 0; k < 8; ++k) acc[k] += __shfl_xor(acc[k], m, 64);
    }

    if (s == 0) {   // lanes 0 (q=0: feats +0..7) and 1 (q=1: feats +8..15)
        float a = alphaT[L];
        #pragma unroll
        for (int k = 0; k < 8; ++k) acc[k] *= a;
        // fp32 out: feat base = half*16 + q*8 -> f32x4 idx rowid*88 + L*8 + half*4 + q*2
        size_t ob = (size_t)rowid * 88 + L * 8 + half * 4 + q * 2;
        f32x4 o0; o0.x = acc[0]; o0.y = acc[1]; o0.z = acc[2]; o0.w = acc[3];
        f32x4 o1; o1.x = acc[4]; o1.y = acc[5]; o1.z = acc[6]; o1.w = acc[7];
        __builtin_nontemporal_store(o0, &out4[ob]);
        __builtin_nontemporal_store(o1, &out4[ob + 1]);
        if (L < DEPTH) {
            u32x4 hh;
            hh.x = pack_bf16x2(acc[0], acc[1]);
            hh.y = pack_bf16x2(acc[2], acc[3]);
            hh.z = pack_bf16x2(acc[4], acc[5]);
            hh.w = pack_bf16x2(acc[6], acc[7]);
            h_cur[(size_t)rowid * 2 + q] = hh;     // plain: next level gathers it
        }
    }
}

// ---------------------------------------------------------------------------
extern "C" void kernel_launch(void* const* d_in, const int* in_sizes, int n_in,
                              void* d_out, int out_size, void* d_ws, size_t ws_size,
                              hipStream_t stream) {
    const float* x      = (const float*)d_in[0];
    const int*   eidx   = (const int*)d_in[1];     // (2, E): row = [0,E), col = [E,2E)
    const float* eattr  = (const float*)d_in[2];
    const float* alphas = (const float*)d_in[3];
    float* out = (float*)d_out;

    const int* row = eidx;
    const int* col = eidx + N_EDGE;

    // ---- workspace partition (256B aligned) ----
    char* p = (char*)d_ws;
    auto alloc = [&](size_t bytes) { char* r = p; p += (bytes + 255) & ~(size_t)255; return (void*)r; };
    int*   cnt       = (int*)  alloc((size_t)N_NODE * 4);
    int*   rowStart  = (int*)  alloc((size_t)(N_NODE + 1) * 4);
    int*   blockSums = (int*)  alloc((size_t)(NB_SCAN + 1) * 4);
    float* dinv      = (float*)alloc((size_t)N_NODE * 4);
    float* alphaT    = (float*)alloc(64);
    u32x4* h0A       = (u32x4*)alloc((size_t)N_NODE * 32);  // bf16 [N][16] halves
    u32x4* h0B       = (u32x4*)alloc((size_t)N_NODE * 32);
    u32x4* t0        = (u32x4*)alloc((size_t)N_NODE * 32);
    u32x4* t1        = (u32x4*)alloc((size_t)N_NODE * 32);
    i32x2* csr       = (i32x2*)alloc((size_t)N_EDGE * 8);
    (void)ws_size; (void)in_sizes; (void)n_in; (void)out_size;

    (void)hipMemsetAsync(cnt, 0, (size_t)N_NODE * 4, stream);

    const int TB = 256;
    int eBlocks = (N_EDGE + TB - 1) / TB;
    int nBlocks = (N_NODE + TB - 1) / TB;

    count_kernel<<<eBlocks, TB, 0, stream>>>(row, cnt, N_EDGE);
    blockscan_kernel<<<NB_SCAN, TB, 0, stream>>>(cnt, rowStart, blockSums, N_NODE);
    scansums_kernel<<<1, 512, 0, stream>>>(blockSums, NB_SCAN);
    addoffs_kernel<<<(N_NODE + 1 + TB - 1) / TB, TB, 0, stream>>>(rowStart, blockSums, N_NODE, NB_SCAN);
    dinv_kernel<<<nBlocks, TB, 0, stream>>>(cnt, dinv, N_NODE);
    scatter_kernel<<<eBlocks, TB, 0, stream>>>(row, col, eattr, rowStart, cnt, dinv, csr, N_EDGE);
    alpha_kernel<<<1, 64, 0, stream>>>(alphas, alphaT);
    copyx_kernel<<<(N_NODE * 8 + TB - 1) / TB, TB, 0, stream>>>((const f32x4*)x, (f32x4*)out,
                                                                (unsigned int*)h0A,
                                                                (unsigned int*)h0B);

    int spmmBlocks = (N_NODE * 64 + TB - 1) / TB;  // one 64-lane wave per row
    for (int half = 0; half < 2; ++half) {
        const u32x4* h0 = (half == 0) ? h0A : h0B;
        for (int L = 1; L <= DEPTH; ++L) {
            const u32x4* hp = (L == 1) ? h0 : ((L & 1) ? t1 : t0);
            u32x4*       hc = (L & 1) ? t0 : t1;
            spmm_half<<<spmmBlocks, TB, 0, stream>>>(rowStart, csr, alphaT, L, half,
                                                     hp, hc, (f32x4*)out);
        }
    }
}

// Round 9
// 566.107 us; speedup vs baseline: 3.4074x; 1.8361x over previous
//
#include <hip/hip_runtime.h>
#include <math.h>

#define N_NODE 100000
#define DEPTH  10
#define N_EDGE 1600000
#define D_FEAT 32
#define D_OUT  ((DEPTH + 1) * D_FEAT)   // 352 floats per node in output
#define NB_SCAN ((N_NODE + 255) / 256)  // 391 scan blocks

// clang-native vector types (accepted by __builtin_nontemporal_*)
typedef float        f32x4 __attribute__((ext_vector_type(4)));
typedef unsigned int u32x4 __attribute__((ext_vector_type(4)));
typedef int          i32x2 __attribute__((ext_vector_type(2)));

// ---------------------------------------------------------------------------
// bf16 helpers (bit-level, RTN-even)
// ---------------------------------------------------------------------------
__device__ inline unsigned short f32_to_bf16(float f) {
    unsigned int b = __float_as_uint(f);
    unsigned int r = (b + 0x7FFFu + ((b >> 16) & 1u)) >> 16;
    return (unsigned short)r;
}
__device__ inline unsigned int pack_bf16x2(float lo, float hi) {
    return (unsigned int)f32_to_bf16(lo) | ((unsigned int)f32_to_bf16(hi) << 16);
}

// ---------------------------------------------------------------------------
// Phase 1: degree count (in-degree over `row`)
// ---------------------------------------------------------------------------
__global__ void count_kernel(const int* __restrict__ row, int* __restrict__ cnt, int E) {
    int e = blockIdx.x * blockDim.x + threadIdx.x;
    if (e < E) atomicAdd(&cnt[row[e]], 1);
}

// ---------------------------------------------------------------------------
// Phase 2: hierarchical exclusive scan (3 kernels)
// ---------------------------------------------------------------------------
__device__ inline int wave_incl_scan(int v) {
    int lane = threadIdx.x & 63;
    #pragma unroll
    for (int off = 1; off < 64; off <<= 1) {
        int t = __shfl_up(v, off, 64);
        if (lane >= off) v += t;
    }
    return v;
}

__global__ void blockscan_kernel(const int* __restrict__ cnt, int* __restrict__ rowStart,
                                 int* __restrict__ blockSums, int n) {
    __shared__ int partials[4];
    int i = blockIdx.x * 256 + threadIdx.x;
    int v = (i < n) ? cnt[i] : 0;
    int incl = wave_incl_scan(v);
    int wid = threadIdx.x >> 6, lane = threadIdx.x & 63;
    if (lane == 63) partials[wid] = incl;
    __syncthreads();
    int woff = 0;
    #pragma unroll
    for (int w = 0; w < 4; ++w) woff += (w < wid) ? partials[w] : 0;
    if (i < n) rowStart[i] = woff + incl - v;               // block-local exclusive
    if (threadIdx.x == 255) blockSums[blockIdx.x] = woff + incl;
}

__global__ void scansums_kernel(int* __restrict__ blockSums, int nb) {
    __shared__ int partials[8];
    int i = threadIdx.x;                                    // 512 threads
    int v = (i < nb) ? blockSums[i] : 0;
    int incl = wave_incl_scan(v);
    int wid = i >> 6, lane = i & 63;
    if (lane == 63) partials[wid] = incl;
    __syncthreads();
    int woff = 0;
    #pragma unroll
    for (int w = 0; w < 8; ++w) woff += (w < wid) ? partials[w] : 0;
    if (i < nb) blockSums[i] = woff + incl - v;             // exclusive
    if (i == 511) blockSums[nb] = woff + incl;              // grand total
}

__global__ void addoffs_kernel(int* __restrict__ rowStart, const int* __restrict__ blockSums,
                               int n, int nb) {
    int i = blockIdx.x * 256 + threadIdx.x;
    if (i < n)  rowStart[i] += blockSums[i >> 8];
    if (i == n) rowStart[n] = blockSums[nb];
}

// ---------------------------------------------------------------------------
// Phase 3: dinv = (deg<0.5 ? deg+1 : deg)^-0.5
// ---------------------------------------------------------------------------
__global__ void dinv_kernel(const int* __restrict__ cnt, float* __restrict__ dinv, int n) {
    int i = blockIdx.x * blockDim.x + threadIdx.x;
    if (i < n) {
        float d = (float)cnt[i];
        if (d < 0.5f) d += 1.0f;
        dinv[i] = 1.0f / sqrtf(d);
    }
}

// ---------------------------------------------------------------------------
// Phase 4: scatter edges to CSR as combined 8B {col, val} entries (NT store).
// ---------------------------------------------------------------------------
__global__ void scatter_kernel(const int* __restrict__ row, const int* __restrict__ col,
                               const float* __restrict__ eattr,
                               const int* __restrict__ rowStart, int* __restrict__ cnt,
                               const float* __restrict__ dinv,
                               i32x2* __restrict__ csr, int E) {
    int e = blockIdx.x * blockDim.x + threadIdx.x;
    if (e < E) {
        int r = row[e], c = col[e];
        int p = rowStart[r] + atomicSub(&cnt[r], 1) - 1;
        float val = dinv[r] * eattr[e] * dinv[c];
        i32x2 ent; ent.x = c; ent.y = __float_as_int(val);
        __builtin_nontemporal_store(ent, &csr[p]);
    }
}

// ---------------------------------------------------------------------------
// alphas_t[L] = tanh(alphas[L]) (BASE_ALPHA = 1)
// ---------------------------------------------------------------------------
__global__ void alpha_kernel(const float* __restrict__ alphas, float* __restrict__ alphaT) {
    int i = threadIdx.x;
    if (i <= DEPTH) alphaT[i] = tanhf(alphas[i]);
}

// ---------------------------------------------------------------------------
// x_0: out[node,0,:] = x (fp32, nt) and h0[node,:] = bf16(x) (plain store)
// h0 layout: word w of node = feats {2w, 2w+1}; 16 words = 64B per node.
// ---------------------------------------------------------------------------
__global__ void copyx_kernel(const f32x4* __restrict__ x4, f32x4* __restrict__ out4,
                             unsigned int* __restrict__ h0) {
    int i = blockIdx.x * blockDim.x + threadIdx.x;
    if (i < N_NODE * 8) {
        int node = i >> 3, q = i & 7;
        f32x4 v = x4[i];
        __builtin_nontemporal_store(v, &out4[(size_t)node * 88 + q]);
        h0[(size_t)node * 16 + q * 2]     = pack_bf16x2(v.x, v.y);
        h0[(size_t)node * 16 + q * 2 + 1] = pack_bf16x2(v.z, v.w);
    }
}

// ---------------------------------------------------------------------------
// Phase 5 (x10): SpMM level L. FOUR ROWS PER WAVE, batched issue:
// per batch-iteration, all 4 rows' csr loads issue together, then all 4
// gathers -> 4 independent memory chains in flight per wave (latency fix).
// lane = (s,q): s = lane>>2 (16 edge slots), q = lane&3 (16B = 8 feats).
// Inactive slots: clamped address + v=0 (no divergence).
// csr NT (streamed); out NT (never re-read); h_cur plain (L2 for next level).
// ---------------------------------------------------------------------------
__global__ __launch_bounds__(256) void spmm_quad(const int* __restrict__ rowStart,
                                                 const i32x2* __restrict__ csr,
                                                 const float* __restrict__ alphaT,
                                                 int L,
                                                 const u32x4* __restrict__ h_prev,
                                                 u32x4* __restrict__ h_cur,
                                                 f32x4* __restrict__ out4) {
    int wave = (int)((blockIdx.x * 256 + threadIdx.x) >> 6);   // 25000 waves exactly
    int lane = threadIdx.x & 63;
    int s = lane >> 2;                 // edge slot (16)
    int q = lane & 3;                  // feat oct (4 x 8 feats)
    int base = wave * 4;               // rows base..base+3 (N_NODE % 4 == 0)

    int rs[5];
    #pragma unroll
    for (int i = 0; i < 5; ++i) rs[i] = rowStart[base + i];

    int be[4], en[4];
    #pragma unroll
    for (int r = 0; r < 4; ++r) { be[r] = rs[r]; en[r] = rs[r + 1]; }

    float acc[4][8];
    #pragma unroll
    for (int r = 0; r < 4; ++r)
        #pragma unroll
        for (int k = 0; k < 8; ++k) acc[r][k] = 0.f;

    while ((be[0] < en[0]) | (be[1] < en[1]) | (be[2] < en[2]) | (be[3] < en[3])) {
        i32x2 cv[4];
        #pragma unroll
        for (int r = 0; r < 4; ++r) {
            int e  = be[r] + s;
            int ec = (e < N_EDGE - 1) ? e : (N_EDGE - 1);
            cv[r] = __builtin_nontemporal_load(&csr[ec]);
        }
        u32x4 hv[4];
        #pragma unroll
        for (int r = 0; r < 4; ++r) {
            hv[r] = h_prev[(size_t)cv[r].x * 4 + q];
        }
        #pragma unroll
        for (int r = 0; r < 4; ++r) {
            float v = (be[r] + s < en[r]) ? __int_as_float(cv[r].y) : 0.f;
            u32x4 h = hv[r];
            acc[r][0] += v * __uint_as_float(h.x << 16);
            acc[r][1] += v * __uint_as_float(h.x & 0xFFFF0000u);
            acc[r][2] += v * __uint_as_float(h.y << 16);
            acc[r][3] += v * __uint_as_float(h.y & 0xFFFF0000u);
            acc[r][4] += v * __uint_as_float(h.z << 16);
            acc[r][5] += v * __uint_as_float(h.z & 0xFFFF0000u);
            acc[r][6] += v * __uint_as_float(h.w << 16);
            acc[r][7] += v * __uint_as_float(h.w & 0xFFFF0000u);
        }
        #pragma unroll
        for (int r = 0; r < 4; ++r) be[r] += 16;
    }

    // reduce across the 16 edge slots (xor 4,8,16,32 preserves q = bits 0..1)
    #pragma unroll
    for (int r = 0; r < 4; ++r)
        #pragma unroll
        for (int m = 4; m < 64; m <<= 1)
            #pragma unroll
            for (int k = 0; k < 8; ++k) acc[r][k] += __shfl_xor(acc[r][k], m, 64);

    if (s == 0) {   // lanes 0..3: lane q holds feats 8q..8q+7 of each row
        float a = alphaT[L];
        #pragma unroll
        for (int r = 0; r < 4; ++r) {
            #pragma unroll
            for (int k = 0; k < 8; ++k) acc[r][k] *= a;
            size_t ob = (size_t)(base + r) * 88 + L * 8 + q * 2;
            f32x4 o0; o0.x = acc[r][0]; o0.y = acc[r][1]; o0.z = acc[r][2]; o0.w = acc[r][3];
            f32x4 o1; o1.x = acc[r][4]; o1.y = acc[r][5]; o1.z = acc[r][6]; o1.w = acc[r][7];
            __builtin_nontemporal_store(o0, &out4[ob]);
            __builtin_nontemporal_store(o1, &out4[ob + 1]);
            if (L < DEPTH) {
                u32x4 hh;
                hh.x = pack_bf16x2(acc[r][0], acc[r][1]);
                hh.y = pack_bf16x2(acc[r][2], acc[r][3]);
                hh.z = pack_bf16x2(acc[r][4], acc[r][5]);
                hh.w = pack_bf16x2(acc[r][6], acc[r][7]);
                h_cur[(size_t)(base + r) * 4 + q] = hh;   // plain: keep in L2
            }
        }
    }
}

// ---------------------------------------------------------------------------
extern "C" void kernel_launch(void* const* d_in, const int* in_sizes, int n_in,
                              void* d_out, int out_size, void* d_ws, size_t ws_size,
                              hipStream_t stream) {
    const float* x      = (const float*)d_in[0];
    const int*   eidx   = (const int*)d_in[1];     // (2, E): row = [0,E), col = [E,2E)
    const float* eattr  = (const float*)d_in[2];
    const float* alphas = (const float*)d_in[3];
    float* out = (float*)d_out;

    const int* row = eidx;
    const int* col = eidx + N_EDGE;

    // ---- workspace partition (256B aligned) ----
    char* p = (char*)d_ws;
    auto alloc = [&](size_t bytes) { char* r = p; p += (bytes + 255) & ~(size_t)255; return (void*)r; };
    int*   cnt       = (int*)  alloc((size_t)N_NODE * 4);
    int*   rowStart  = (int*)  alloc((size_t)(N_NODE + 8) * 4);  // +pad for quad reads
    int*   blockSums = (int*)  alloc((size_t)(NB_SCAN + 1) * 4);
    float* dinv      = (float*)alloc((size_t)N_NODE * 4);
    float* alphaT    = (float*)alloc(64);
    u32x4* h0        = (u32x4*)alloc((size_t)N_NODE * 64);  // bf16 [N][32]
    u32x4* h1        = (u32x4*)alloc((size_t)N_NODE * 64);
    i32x2* csr       = (i32x2*)alloc((size_t)N_EDGE * 8);
    (void)ws_size; (void)in_sizes; (void)n_in; (void)out_size;

    (void)hipMemsetAsync(cnt, 0, (size_t)N_NODE * 4, stream);

    const int TB = 256;
    int eBlocks = (N_EDGE + TB - 1) / TB;
    int nBlocks = (N_NODE + TB - 1) / TB;

    count_kernel<<<eBlocks, TB, 0, stream>>>(row, cnt, N_EDGE);
    blockscan_kernel<<<NB_SCAN, TB, 0, stream>>>(cnt, rowStart, blockSums, N_NODE);
    scansums_kernel<<<1, 512, 0, stream>>>(blockSums, NB_SCAN);
    addoffs_kernel<<<(N_NODE + 1 + TB - 1) / TB, TB, 0, stream>>>(rowStart, blockSums, N_NODE, NB_SCAN);
    dinv_kernel<<<nBlocks, TB, 0, stream>>>(cnt, dinv, N_NODE);
    scatter_kernel<<<eBlocks, TB, 0, stream>>>(row, col, eattr, rowStart, cnt, dinv, csr, N_EDGE);
    alpha_kernel<<<1, 64, 0, stream>>>(alphas, alphaT);
    copyx_kernel<<<(N_NODE * 8 + TB - 1) / TB, TB, 0, stream>>>((const f32x4*)x, (f32x4*)out,
                                                                (unsigned int*)h0);

    int quadBlocks = N_NODE / 4 / 4;   // 25000 waves / 4 waves per block = 6250
    for (int L = 1; L <= DEPTH; ++L) {
        const u32x4* hp = (L & 1) ? h0 : h1;
        u32x4*       hc = (L & 1) ? h1 : h0;
        spmm_quad<<<quadBlocks, TB, 0, stream>>>(rowStart, csr, alphaT, L, hp, hc,
                                                 (f32x4*)out);
    }
}